// Round 11
// baseline (472.426 us; speedup 1.0000x reference)
//
#include <hip/hip_runtime.h>
#include <math.h>

#define H_DIM 7168
#define N_EXP 256
#define N_GRP 8
#define G_SZ  32
#define TOPK_G 4
#define TOPK   8
#define BM 64
#define BK 32
#define S_TOK 16384
#define NTILES (H_DIM / BK)          // 224 total
#define NSPLIT 2
#define NH     (NTILES / NSPLIT)     // 112 per K-half
#define NINT   (NH / 2)              // 56 two-tile intervals
#define TILE_W_BYTES 32768           // per k-tile: [wave 0-7][frag 0-3][lane 0-63][16B]

#define SA_SCALE 256.0f              // A * 2^8   (exact pow2)
#define SW_SCALE 4096.0f             // W * 2^12  (exact pow2)
#define DESCALE  (1.0f / 1048576.0f) // 2^-20

__device__ __align__(256) char g_wimg[(size_t)NTILES * TILE_W_BYTES];        // 7.34 MB
__device__ __align__(256) float g_part[NSPLIT * (size_t)S_TOK * N_EXP];      // 33.5 MB

typedef __attribute__((ext_vector_type(8))) _Float16 f16x8;
typedef __attribute__((ext_vector_type(4))) float f32x4;
typedef __attribute__((ext_vector_type(4))) unsigned short u16x4;
typedef __attribute__((ext_vector_type(8))) unsigned short u16x8;

__device__ inline void split2h(float x, unsigned short& h, unsigned short& l) {
    _Float16 hf = (_Float16)x;                 // RNE
    _Float16 lf = (_Float16)(x - (float)hf);   // exact residual
    h = __builtin_bit_cast(unsigned short, hf);
    l = __builtin_bit_cast(unsigned short, lf);
}

// ---- pre-kernel: fp32 W -> per-wave fragment-contiguous fp16 hi/lo images ----
__global__ __launch_bounds__(256)
void convert_w_kernel(const float* __restrict__ W) {
    int idx  = blockIdx.x * 256 + threadIdx.x;   // e*(H/8) + koct
    int e    = idx / (H_DIM / 8);
    int koct = idx - e * (H_DIM / 8);
    int k0   = koct * 8;
    int t    = k0 >> 5;
    int o    = (k0 >> 3) & 3;
    int lane = (e & 15) | (o << 4);
    int w    = e >> 5;
    int nj   = (e >> 4) & 1;
    const float* src = W + (size_t)e * H_DIM + k0;
    unsigned short h[8], l[8];
    #pragma unroll
    for (int j = 0; j < 8; ++j)
        split2h(src[j] * SW_SCALE, h[j], l[j]);
    char* base = g_wimg + (size_t)t * TILE_W_BYTES + (w << 12) + (lane << 4);
    *(u16x8*)(base + nj * 1024)       = u16x8{h[0],h[1],h[2],h[3],h[4],h[5],h[6],h[7]};
    *(u16x8*)(base + (2 + nj) * 1024) = u16x8{l[0],l[1],l[2],l[3],l[4],l[5],l[6],l[7]};
}

// ---- main GEMM: split-K x2, register-pipelined A-frags + W, 2-tile intervals ----
__global__ __launch_bounds__(512, 4)
void moe_gemm_half(const float* __restrict__ A)
{
    __shared__ __align__(128) char smem[2 * 16384];   // 2 buffers x 2 sub-tiles x 8KB

    const int tid   = threadIdx.x;
    const int lane  = tid & 63;
    const int wave  = tid >> 6;
    const int khalf = blockIdx.x & 1;
    const int brow  = (blockIdx.x >> 1) * BM;

    // fragment read offset (R5..R10-verified swizzle)
    const int fr   = lane & 15;
    const int fkb  = (lane >> 4) << 4;
    const int fswz = ((fr << 6) + fkb) ^ ((fr & 7) << 4);

    // A staging: thread -> row ar (0..63), 4-float chunk akq (0..7)
    const int ar   = tid >> 3;
    const int akq  = tid & 7;
    const int aswz = ((ar << 6) + (akq << 3)) ^ ((ar & 7) << 4);
    const float4* Ag4 = reinterpret_cast<const float4*>(
        A + (size_t)(brow + ar) * H_DIM + khalf * (H_DIM / NSPLIT)) + akq;

    const char* wsrc = g_wimg + (size_t)(khalf * NH) * TILE_W_BYTES
                       + (wave << 12) + (lane << 4);

    f32x4 acc[4][2] = {};

    f16x8 WH0[2], WH1[2], WL0[2], WL1[2];   // W ping-pong by tile parity
    f16x8 AH[2][4], AL[2][4];               // A-frag ping-pong by sub-tile parity

    auto issueW = [&](int t, int p) {
        const char* b = wsrc + (size_t)t * TILE_W_BYTES;
        WH0[p] = *(const f16x8*)(b + 0);
        WH1[p] = *(const f16x8*)(b + 1024);
        WL0[p] = *(const f16x8*)(b + 2048);
        WL1[p] = *(const f16x8*)(b + 3072);
    };
    auto issueAH = [&](const char* sb, int p) {
        #pragma unroll
        for (int mi = 0; mi < 4; ++mi)
            AH[p][mi] = *(const f16x8*)(sb + mi * 1024 + fswz);
    };
    auto issueAL = [&](const char* sb, int p) {
        #pragma unroll
        for (int mi = 0; mi < 4; ++mi)
            AL[p][mi] = *(const f16x8*)(sb + 4096 + mi * 1024 + fswz);
    };
    auto passHH = [&](int p) {
        __builtin_amdgcn_s_setprio(1);
        #pragma unroll
        for (int mi = 0; mi < 4; ++mi)
            acc[mi][0] = __builtin_amdgcn_mfma_f32_16x16x32_f16(AH[p][mi], WH0[p], acc[mi][0], 0, 0, 0);
        #pragma unroll
        for (int mi = 0; mi < 4; ++mi)
            acc[mi][1] = __builtin_amdgcn_mfma_f32_16x16x32_f16(AH[p][mi], WH1[p], acc[mi][1], 0, 0, 0);
        __builtin_amdgcn_s_setprio(0);
    };
    auto passLH = [&](int p) {
        __builtin_amdgcn_s_setprio(1);
        #pragma unroll
        for (int mi = 0; mi < 4; ++mi)
            acc[mi][0] = __builtin_amdgcn_mfma_f32_16x16x32_f16(AL[p][mi], WH0[p], acc[mi][0], 0, 0, 0);
        #pragma unroll
        for (int mi = 0; mi < 4; ++mi)
            acc[mi][1] = __builtin_amdgcn_mfma_f32_16x16x32_f16(AL[p][mi], WH1[p], acc[mi][1], 0, 0, 0);
        __builtin_amdgcn_s_setprio(0);
    };
    auto passHL = [&](int p) {
        __builtin_amdgcn_s_setprio(1);
        #pragma unroll
        for (int mi = 0; mi < 4; ++mi)
            acc[mi][0] = __builtin_amdgcn_mfma_f32_16x16x32_f16(AH[p][mi], WL0[p], acc[mi][0], 0, 0, 0);
        #pragma unroll
        for (int mi = 0; mi < 4; ++mi)
            acc[mi][1] = __builtin_amdgcn_mfma_f32_16x16x32_f16(AH[p][mi], WL1[p], acc[mi][1], 0, 0, 0);
        __builtin_amdgcn_s_setprio(0);
    };
    auto writeA = [&](const float4& v, char* ab) {
        unsigned short h[4], l[4];
        split2h(v.x * SA_SCALE, h[0], l[0]); split2h(v.y * SA_SCALE, h[1], l[1]);
        split2h(v.z * SA_SCALE, h[2], l[2]); split2h(v.w * SA_SCALE, h[3], l[3]);
        *(u16x4*)(ab + aswz)        = u16x4{h[0], h[1], h[2], h[3]};
        *(u16x4*)(ab + 4096 + aswz) = u16x4{l[0], l[1], l[2], l[3]};
    };

    // ---- prologue: stage interval 0, preload W(0), load frags(tile 0) ----
    {
        float4 a0 = Ag4[0], a1 = Ag4[8];
        issueW(0, 0);
        writeA(a0, smem);
        writeA(a1, smem + 8192);
        asm volatile("s_waitcnt lgkmcnt(0)" ::: "memory");
        __builtin_amdgcn_s_barrier();
        issueAH(smem, 0);
        issueAL(smem, 0);
    }

    // ---- main loop: 56 intervals x 2 tiles ----
    #pragma unroll 1
    for (int i = 0; i < NINT; ++i) {
        char* cur = smem + (i & 1) * 16384;
        char* nxt = smem + ((i + 1) & 1) * 16384;
        const int t0 = i * 2;
        const bool hn = (i + 1 < NINT);

        // sub-tile 0 (tile t0, A-parity 0, W-parity 0)
        float4 an0, an1;
        if (hn) { an0 = Ag4[(size_t)(t0 + 2) * 8]; an1 = Ag4[(size_t)(t0 + 3) * 8]; }
        issueW(t0 + 1, 1);
        issueAH(cur + 8192, 1);    // next sub-tile's AH in flight under MFMAs
        passHH(0);
        passLH(0);
        issueAL(cur + 8192, 1);    // AL[0] dead now; AL[1] reuses its slots
        passHL(0);

        // sub-tile 1 (tile t0+1, A-parity 1, W-parity 1)
        if (hn) {
            issueW(t0 + 2, 0);
            writeA(an0, nxt);            // vm-wait lands here (~900cy after issue)
            writeA(an1, nxt + 8192);
        }
        passHH(1);
        passLH(1);
        passHL(1);
        asm volatile("s_waitcnt lgkmcnt(0)" ::: "memory");
        __builtin_amdgcn_s_barrier();
        if (hn) {                         // post-barrier: next interval's tile-0 frags
            issueAH(nxt, 0);
            issueAL(nxt, 0);
        }
    }

    // ---- store raw fp32 partials ----
    float* pb = g_part + ((size_t)khalf * S_TOK + brow) * N_EXP;
    #pragma unroll
    for (int mi = 0; mi < 4; ++mi)
        #pragma unroll
        for (int nj = 0; nj < 2; ++nj)
            #pragma unroll
            for (int q = 0; q < 4; ++q) {
                int row = mi * 16 + ((lane >> 4) << 2) + q;
                int col = wave * 32 + nj * 16 + (lane & 15);
                pb[row * N_EXP + col] = acc[mi][nj][q];
            }
}

// ---- gating: one wave per token row, fully wave-parallel (R8-proven) ----
__global__ __launch_bounds__(256)
void gate_kernel(const float* __restrict__ bias, float* __restrict__ out, int S)
{
    const int lane = threadIdx.x & 63;
    const int row  = (blockIdx.x * 256 + threadIdx.x) >> 6;

    const float4 p0 = *(const float4*)(g_part + (size_t)row * N_EXP + lane * 4);
    const float4 p1 = *(const float4*)(g_part + ((size_t)S_TOK + row) * N_EXP + lane * 4);
    const float4 b4 = *(const float4*)(bias + lane * 4);

    float s[4], v[4];
    float m1 = -1e30f, m2 = -1e30f;
    {
        const float* q0 = (const float*)&p0;
        const float* q1 = (const float*)&p1;
        const float* qb = (const float*)&b4;
        #pragma unroll
        for (int j = 0; j < 4; ++j) {
            float x = (q0[j] + q1[j]) * DESCALE;
            s[j] = 1.0f / (1.0f + expf(-x));
            float sb = s[j] + qb[j];
            v[j] = sb;
            if (sb > m1) { m2 = m1; m1 = sb; } else if (sb > m2) { m2 = sb; }
        }
    }
    #pragma unroll
    for (int d = 1; d < 8; d <<= 1) {
        float om1 = __shfl_xor(m1, d), om2 = __shfl_xor(m2, d);
        float hi = fmaxf(m1, om1), lo = fminf(m1, om1);
        m1 = hi;
        m2 = fmaxf(lo, fmaxf(m2, om2));
    }
    float gs = m1 + m2;
    float gsv[8];
    #pragma unroll
    for (int g = 0; g < 8; ++g) gsv[g] = __shfl(gs, g << 3);

    unsigned gmask = 0;
    #pragma unroll
    for (int t = 0; t < TOPK_G; ++t) {
        float best = -1e30f; int bg = 0;
        #pragma unroll
        for (int g = 0; g < 8; ++g) {
            bool avail = !((gmask >> g) & 1);
            if (avail && gsv[g] > best) { best = gsv[g]; bg = g; }
        }
        gmask |= 1u << bg;
    }

    const bool sel = (gmask >> (lane >> 3)) & 1;
    #pragma unroll
    for (int j = 0; j < 4; ++j) v[j] = sel ? v[j] : 0.0f;

    float wv[TOPK]; int wi[TOPK]; float wsum = 0.0f;
    #pragma unroll
    for (int t = 0; t < TOPK; ++t) {
        float bv = v[0]; int bj = 0;
        #pragma unroll
        for (int j = 1; j < 4; ++j)
            if (v[j] > bv) { bv = v[j]; bj = j; }
        int bidx = (lane << 2) | bj;
        #pragma unroll
        for (int d = 32; d >= 1; d >>= 1) {
            float ov = __shfl_xor(bv, d);
            int   oi = __shfl_xor(bidx, d);
            if (ov > bv || (ov == bv && oi < bidx)) { bv = ov; bidx = oi; }
        }
        int ol = bidx >> 2, oj = bidx & 3;
        float sl = s[0];
        if (oj == 1) sl = s[1]; else if (oj == 2) sl = s[2]; else if (oj == 3) sl = s[3];
        float sv = __shfl(sl, ol);      // UNBIASED score for the weight
        wv[t] = sv; wi[t] = bidx; wsum += sv;
        if (lane == ol) {
            if (oj == 0) v[0] = -1e30f; else if (oj == 1) v[1] = -1e30f;
            else if (oj == 2) v[2] = -1e30f; else v[3] = -1e30f;
        }
    }

    if (lane == 0) {
        float scale = 2.5f / (wsum + 1e-20f);
        #pragma unroll
        for (int t = 0; t < TOPK; ++t) {
            out[(size_t)row * TOPK + t] = wv[t] * scale;
            out[(size_t)S * TOPK + (size_t)row * TOPK + t] = (float)wi[t];
        }
    }
}

extern "C" void kernel_launch(void* const* d_in, const int* in_sizes, int n_in,
                              void* d_out, int out_size, void* d_ws, size_t ws_size,
                              hipStream_t stream) {
    const float* A    = (const float*)d_in[0];
    const float* W    = (const float*)d_in[1];
    const float* bias = (const float*)d_in[2];
    float* out = (float*)d_out;
    const int S = in_sizes[0] / H_DIM;   // 16384

    convert_w_kernel<<<dim3(N_EXP * (H_DIM / 8) / 256), 256, 0, stream>>>(W);
    moe_gemm_half<<<dim3(NSPLIT * S / BM), 512, 0, stream>>>(A);
    gate_kernel<<<dim3(S / 4), 256, 0, stream>>>(bias, out, S);
}

// Round 12
// 217.687 us; speedup vs baseline: 2.1702x; 2.1702x over previous
//
#include <hip/hip_runtime.h>
#include <math.h>

#define H_DIM 7168
#define N_EXP 256
#define N_GRP 8
#define G_SZ  32
#define TOPK_G 4
#define TOPK   8
#define BM 64
#define BK 32
#define S_TOK 16384
#define NTILES (H_DIM / BK)          // 224 total
#define NSPLIT 2
#define NH     (NTILES / NSPLIT)     // 112 per K-half
#define ITILES 4                     // k-tiles per barrier interval
#define NINT   (NH / ITILES)         // 28 intervals
#define TILE_W_BYTES 32768           // per k-tile: [wave 0-7][frag 0-3][lane 0-63][16B]

#define SA_SCALE 256.0f              // A * 2^8   (exact pow2)
#define SW_SCALE 4096.0f             // W * 2^12  (exact pow2)
#define DESCALE  (1.0f / 1048576.0f) // 2^-20

__device__ __align__(256) char g_wimg[(size_t)NTILES * TILE_W_BYTES];        // 7.34 MB
__device__ __align__(256) float g_part[NSPLIT * (size_t)S_TOK * N_EXP];      // 33.5 MB

typedef __attribute__((ext_vector_type(8))) _Float16 f16x8;
typedef __attribute__((ext_vector_type(4))) float f32x4;
typedef __attribute__((ext_vector_type(4))) unsigned short u16x4;
typedef __attribute__((ext_vector_type(8))) unsigned short u16x8;

__device__ inline void split2h(float x, unsigned short& h, unsigned short& l) {
    _Float16 hf = (_Float16)x;                 // RNE
    _Float16 lf = (_Float16)(x - (float)hf);   // exact residual
    h = __builtin_bit_cast(unsigned short, hf);
    l = __builtin_bit_cast(unsigned short, lf);
}

// ---- pre-kernel: fp32 W -> per-wave fragment-contiguous fp16 hi/lo images ----
__global__ __launch_bounds__(256)
void convert_w_kernel(const float* __restrict__ W) {
    int idx  = blockIdx.x * 256 + threadIdx.x;   // e*(H/8) + koct
    int e    = idx / (H_DIM / 8);
    int koct = idx - e * (H_DIM / 8);
    int k0   = koct * 8;
    int t    = k0 >> 5;
    int o    = (k0 >> 3) & 3;
    int lane = (e & 15) | (o << 4);
    int w    = e >> 5;
    int nj   = (e >> 4) & 1;
    const float* src = W + (size_t)e * H_DIM + k0;
    unsigned short h[8], l[8];
    #pragma unroll
    for (int j = 0; j < 8; ++j)
        split2h(src[j] * SW_SCALE, h[j], l[j]);
    char* base = g_wimg + (size_t)t * TILE_W_BYTES + (w << 12) + (lane << 4);
    *(u16x8*)(base + nj * 1024)       = u16x8{h[0],h[1],h[2],h[3],h[4],h[5],h[6],h[7]};
    *(u16x8*)(base + (2 + nj) * 1024) = u16x8{l[0],l[1],l[2],l[3],l[4],l[5],l[6],l[7]};
}

// ---- main GEMM: split-K x2, 4-tile barrier intervals, W in regs ----
// launch_bounds(512,2): empirically arg2 = workgroups/CU on hipcc ->
// 2 blocks/CU = 4 waves/SIMD = 128-VGPR cap (R9/R11 showed (512,4/8) -> 64/32 VGPR + spill)
__global__ __launch_bounds__(512, 2)
void moe_gemm_half(const float* __restrict__ A)
{
    __shared__ __align__(128) char smem[2 * ITILES * 8192];   // 64 KB

    const int tid   = threadIdx.x;
    const int lane  = tid & 63;
    const int wave  = tid >> 6;
    // XCD-aware decode: blocks with (b&7)<4 -> khalf 0, else khalf 1.
    // Round-robin XCD assignment then keeps each XCD's W working set at one
    // 3.67MB half-image (fits 4MB L2) instead of 7.34MB (thrash).
    const int b     = blockIdx.x;
    const int khalf = (b >> 2) & 1;
    const int brow  = ((b >> 3) * 4 + (b & 3)) * BM;
    const int g0    = khalf * NH;       // base tile in g_wimg

    // fragment read offset (R5..R10-verified swizzle)
    const int fr   = lane & 15;
    const int fkb  = (lane >> 4) << 4;
    const int fswz = ((fr << 6) + fkb) ^ ((fr & 7) << 4);

    // A staging: thread -> row ar (0..63), 4-float chunk akq (0..7)
    const int ar   = tid >> 3;
    const int akq  = tid & 7;
    const int aswz = ((ar << 6) + (akq << 3)) ^ ((ar & 7) << 4);
    const float4* Ag4 = reinterpret_cast<const float4*>(
        A + (size_t)(brow + ar) * H_DIM + khalf * (H_DIM / NSPLIT)) + akq;

    const char* wsrc = g_wimg + (size_t)g0 * TILE_W_BYTES + (wave << 12) + (lane << 4);

    f32x4 acc[4][2] = {};

    auto loadW = [&](int t, f16x8& h0, f16x8& h1, f16x8& l0, f16x8& l1) {
        const char* p = wsrc + (size_t)t * TILE_W_BYTES;
        h0 = *(const f16x8*)(p + 0);
        h1 = *(const f16x8*)(p + 1024);
        l0 = *(const f16x8*)(p + 2048);
        l1 = *(const f16x8*)(p + 3072);
    };

    auto writeA = [&](const float4& v, char* ab) {
        unsigned short h[4], l[4];
        split2h(v.x * SA_SCALE, h[0], l[0]); split2h(v.y * SA_SCALE, h[1], l[1]);
        split2h(v.z * SA_SCALE, h[2], l[2]); split2h(v.w * SA_SCALE, h[3], l[3]);
        *(u16x4*)(ab + aswz)        = u16x4{h[0], h[1], h[2], h[3]};
        *(u16x4*)(ab + 4096 + aswz) = u16x4{l[0], l[1], l[2], l[3]};
    };

    // 3-pass MFMA order: per-acc sequence stays hh, lh, hl (bit-identical)
    auto compute = [&](const char* ab, f16x8 bh0, f16x8 bh1, f16x8 bl0, f16x8 bl1) {
        f16x8 ah[4], al[4];
        #pragma unroll
        for (int mi = 0; mi < 4; ++mi) {
            ah[mi] = *(const f16x8*)(ab + mi * 1024 + fswz);
            al[mi] = *(const f16x8*)(ab + 4096 + mi * 1024 + fswz);
        }
        __builtin_amdgcn_s_setprio(1);
        #pragma unroll
        for (int mi = 0; mi < 4; ++mi)
            acc[mi][0] = __builtin_amdgcn_mfma_f32_16x16x32_f16(ah[mi], bh0, acc[mi][0], 0, 0, 0);
        #pragma unroll
        for (int mi = 0; mi < 4; ++mi)
            acc[mi][1] = __builtin_amdgcn_mfma_f32_16x16x32_f16(ah[mi], bh1, acc[mi][1], 0, 0, 0);
        #pragma unroll
        for (int mi = 0; mi < 4; ++mi)
            acc[mi][0] = __builtin_amdgcn_mfma_f32_16x16x32_f16(al[mi], bh0, acc[mi][0], 0, 0, 0);
        #pragma unroll
        for (int mi = 0; mi < 4; ++mi)
            acc[mi][1] = __builtin_amdgcn_mfma_f32_16x16x32_f16(al[mi], bh1, acc[mi][1], 0, 0, 0);
        #pragma unroll
        for (int mi = 0; mi < 4; ++mi)
            acc[mi][0] = __builtin_amdgcn_mfma_f32_16x16x32_f16(ah[mi], bl0, acc[mi][0], 0, 0, 0);
        #pragma unroll
        for (int mi = 0; mi < 4; ++mi)
            acc[mi][1] = __builtin_amdgcn_mfma_f32_16x16x32_f16(ah[mi], bl1, acc[mi][1], 0, 0, 0);
        __builtin_amdgcn_s_setprio(0);
    };

    // W register pipeline: x = front (tile t), y = next (t+1)
    f16x8 xh0, xh1, xl0, xl1;
    f16x8 yh0, yh1, yl0, yl1;

    // ---- prologue: stage interval 0, preload W(0),W(1) ----
    {
        char* b0 = smem;
        float4 a0[ITILES];
        #pragma unroll
        for (int s = 0; s < ITILES; ++s) a0[s] = Ag4[(size_t)s * 8];
        loadW(0, xh0, xh1, xl0, xl1);
        loadW(1, yh0, yh1, yl0, yl1);
        #pragma unroll
        for (int s = 0; s < ITILES; ++s) writeA(a0[s], b0 + s * 8192);
        asm volatile("s_waitcnt lgkmcnt(0)" ::: "memory");
        __builtin_amdgcn_s_barrier();
    }

    // ---- main loop: 28 intervals x 4 tiles, one barrier per interval ----
    #pragma unroll 1
    for (int i = 0; i < NINT; ++i) {
        char* cur = smem + (i & 1) * (ITILES * 8192);
        char* nxt = smem + ((i + 1) & 1) * (ITILES * 8192);
        const bool havenext = (i + 1 < NINT);
        const int ibase = (havenext ? i + 1 : i) * ITILES;

        // issue next interval's A loads early (consumed after sub-tile 1)
        float4 an[ITILES];
        #pragma unroll
        for (int s = 0; s < ITILES; ++s) an[s] = Ag4[(size_t)(ibase + s) * 8];

        #pragma unroll
        for (int s = 0; s < ITILES; ++s) {
            const int t = i * ITILES + s;
            const int tpf = (t + 2 < NH) ? t + 2 : NH - 1;
            f16x8 nh0, nh1, nl0, nl1;
            loadW(tpf, nh0, nh1, nl0, nl1);
            compute(cur + s * 8192, xh0, xh1, xl0, xl1);
            if (s == 1 && havenext) {
                #pragma unroll
                for (int ss = 0; ss < ITILES; ++ss)
                    writeA(an[ss], nxt + ss * 8192);
            }
            xh0 = yh0; xh1 = yh1; xl0 = yl0; xl1 = yl1;
            yh0 = nh0; yh1 = nh1; yl0 = nl0; yl1 = nl1;
        }
        asm volatile("s_waitcnt lgkmcnt(0)" ::: "memory");
        __builtin_amdgcn_s_barrier();
    }

    // ---- store raw fp32 partials ----
    float* pb = g_part + ((size_t)khalf * S_TOK + brow) * N_EXP;
    #pragma unroll
    for (int mi = 0; mi < 4; ++mi)
        #pragma unroll
        for (int nj = 0; nj < 2; ++nj)
            #pragma unroll
            for (int q = 0; q < 4; ++q) {
                int row = mi * 16 + ((lane >> 4) << 2) + q;
                int col = wave * 32 + nj * 16 + (lane & 15);
                pb[row * N_EXP + col] = acc[mi][nj][q];
            }
}

// ---- gating: one wave per token row, fully wave-parallel (R8-proven) ----
__global__ __launch_bounds__(256)
void gate_kernel(const float* __restrict__ bias, float* __restrict__ out, int S)
{
    const int lane = threadIdx.x & 63;
    const int row  = (blockIdx.x * 256 + threadIdx.x) >> 6;

    const float4 p0 = *(const float4*)(g_part + (size_t)row * N_EXP + lane * 4);
    const float4 p1 = *(const float4*)(g_part + ((size_t)S_TOK + row) * N_EXP + lane * 4);
    const float4 b4 = *(const float4*)(bias + lane * 4);

    float s[4], v[4];
    float m1 = -1e30f, m2 = -1e30f;
    {
        const float* q0 = (const float*)&p0;
        const float* q1 = (const float*)&p1;
        const float* qb = (const float*)&b4;
        #pragma unroll
        for (int j = 0; j < 4; ++j) {
            float x = (q0[j] + q1[j]) * DESCALE;
            s[j] = 1.0f / (1.0f + expf(-x));
            float sb = s[j] + qb[j];
            v[j] = sb;
            if (sb > m1) { m2 = m1; m1 = sb; } else if (sb > m2) { m2 = sb; }
        }
    }
    #pragma unroll
    for (int d = 1; d < 8; d <<= 1) {
        float om1 = __shfl_xor(m1, d), om2 = __shfl_xor(m2, d);
        float hi = fmaxf(m1, om1), lo = fminf(m1, om1);
        m1 = hi;
        m2 = fmaxf(lo, fmaxf(m2, om2));
    }
    float gs = m1 + m2;
    float gsv[8];
    #pragma unroll
    for (int g = 0; g < 8; ++g) gsv[g] = __shfl(gs, g << 3);

    unsigned gmask = 0;
    #pragma unroll
    for (int t = 0; t < TOPK_G; ++t) {
        float best = -1e30f; int bg = 0;
        #pragma unroll
        for (int g = 0; g < 8; ++g) {
            bool avail = !((gmask >> g) & 1);
            if (avail && gsv[g] > best) { best = gsv[g]; bg = g; }
        }
        gmask |= 1u << bg;
    }

    const bool sel = (gmask >> (lane >> 3)) & 1;
    #pragma unroll
    for (int j = 0; j < 4; ++j) v[j] = sel ? v[j] : 0.0f;

    float wv[TOPK]; int wi[TOPK]; float wsum = 0.0f;
    #pragma unroll
    for (int t = 0; t < TOPK; ++t) {
        float bv = v[0]; int bj = 0;
        #pragma unroll
        for (int j = 1; j < 4; ++j)
            if (v[j] > bv) { bv = v[j]; bj = j; }
        int bidx = (lane << 2) | bj;
        #pragma unroll
        for (int d = 32; d >= 1; d >>= 1) {
            float ov = __shfl_xor(bv, d);
            int   oi = __shfl_xor(bidx, d);
            if (ov > bv || (ov == bv && oi < bidx)) { bv = ov; bidx = oi; }
        }
        int ol = bidx >> 2, oj = bidx & 3;
        float sl = s[0];
        if (oj == 1) sl = s[1]; else if (oj == 2) sl = s[2]; else if (oj == 3) sl = s[3];
        float sv = __shfl(sl, ol);      // UNBIASED score for the weight
        wv[t] = sv; wi[t] = bidx; wsum += sv;
        if (lane == ol) {
            if (oj == 0) v[0] = -1e30f; else if (oj == 1) v[1] = -1e30f;
            else if (oj == 2) v[2] = -1e30f; else v[3] = -1e30f;
        }
    }

    if (lane == 0) {
        float scale = 2.5f / (wsum + 1e-20f);
        #pragma unroll
        for (int t = 0; t < TOPK; ++t) {
            out[(size_t)row * TOPK + t] = wv[t] * scale;
            out[(size_t)S * TOPK + (size_t)row * TOPK + t] = (float)wi[t];
        }
    }
}

extern "C" void kernel_launch(void* const* d_in, const int* in_sizes, int n_in,
                              void* d_out, int out_size, void* d_ws, size_t ws_size,
                              hipStream_t stream) {
    const float* A    = (const float*)d_in[0];
    const float* W    = (const float*)d_in[1];
    const float* bias = (const float*)d_in[2];
    float* out = (float*)d_out;
    const int S = in_sizes[0] / H_DIM;   // 16384

    convert_w_kernel<<<dim3(N_EXP * (H_DIM / 8) / 256), 256, 0, stream>>>(W);
    moe_gemm_half<<<dim3(NSPLIT * S / BM), 512, 0, stream>>>(A);
    gate_kernel<<<dim3(S / 4), 256, 0, stream>>>(bias, out, S);
}